// Round 1
// baseline (319.228 us; speedup 1.0000x reference)
//
#include <hip/hip_runtime.h>
#include <hip/hip_bf16.h>

#define BB   8
#define NN   64
#define EMB  32
#define CD   24
#define NL   3
#define NB_  3
#define HH   100
#define LU   72            // NL*CD
#define COUT 248           // CLOUD_OUT = CD*9 + EMB
#define RESO 496
#define FF   128

__device__ __forceinline__ float sp5(float x) {
    // softplus(5x)/5, stable: max(z,0)+log1p(exp(-|z|)), z=5x
    float z = 5.0f * x;
    return 0.2f * (fmaxf(z, 0.0f) + log1pf(expf(-fabsf(z))));
}

// ---------------- K1: per-(b,j) block: W3f + pair MLP + contraction -> t ----
__global__ __launch_bounds__(256) void k1_pairs(
    const float* __restrict__ xyz, const int* __restrict__ feat,
    const float* __restrict__ emb,
    const float* __restrict__ rW1, const float* __restrict__ rb1,
    const float* __restrict__ rW2, const float* __restrict__ rb2,
    const float* __restrict__ rW3, const float* __restrict__ rb3,
    float* __restrict__ tbuf)
{
    const int b   = blockIdx.x / NN;
    const int j   = blockIdx.x % NN;
    const int tid = threadIdx.x;

    __shared__ float xi[NN * 3];          // 768 B
    __shared__ float fj[EMB];             // 128 B
    __shared__ float W3f[HH * LU];        // 28800 B
    __shared__ float tb[LU];              // 288 B
    __shared__ float rW2s[HH * HH];       // 40000 B
    __shared__ float bas[8][NB_];         // 96 B
    __shared__ float h1[8][HH];           // 3200 B
    __shared__ float h2[8][HH];           // 3200 B

    if (tid < NN * 3) xi[tid] = xyz[b * NN * 3 + tid];
    if (tid >= 192 && tid < 192 + EMB)
        fj[tid - 192] = emb[feat[b * NN + j] * EMB + (tid - 192)];
    for (int idx = tid; idx < HH * HH; idx += 256) rW2s[idx] = rW2[idx];
    __syncthreads();

    const float xjx = xi[j * 3 + 0], xjy = xi[j * 3 + 1], xjz = xi[j * 3 + 2];

    // W3f[k][lu] = sum_v rW3[k, lu*32+v] * f[b,j,v]
    for (int idx = tid; idx < HH * LU; idx += 256) {
        const int k  = idx / LU;
        const int lu = idx - k * LU;
        const float4* w = reinterpret_cast<const float4*>(rW3 + (size_t)k * (LU * EMB) + lu * EMB);
        float acc = 0.f;
#pragma unroll
        for (int v4 = 0; v4 < EMB / 4; ++v4) {
            float4 wv = w[v4];
            acc += wv.x * fj[4 * v4 + 0] + wv.y * fj[4 * v4 + 1]
                 + wv.z * fj[4 * v4 + 2] + wv.w * fj[4 * v4 + 3];
        }
        W3f[idx] = acc;
    }
    if (tid < LU) {
        const float* w = rb3 + tid * EMB;
        float acc = 0.f;
#pragma unroll
        for (int v = 0; v < EMB; ++v) acc += w[v] * fj[v];
        tb[tid] = acc;
    }
    __syncthreads();

    for (int t0 = 0; t0 < NN; t0 += 8) {
        if (tid < 8) {
            const int i = t0 + tid;
            const float dx = xjx - xi[i * 3 + 0];
            const float dy = xjy - xi[i * 3 + 1];
            const float dz = xjz - xi[i * 3 + 2];
            const float d  = sqrtf(dx * dx + dy * dy + dz * dz + 1e-8f);
#pragma unroll
            for (int r = 0; r < NB_; ++r) {
                const float u = fabsf(d - (float)r);   // radii = {0,1,2}, step = 1
                const float c = cosf(1.57079632679489662f * u);
                bas[tid][r] = (u < 1.0f) ? c * c : 0.0f;
            }
        }
        __syncthreads();
        // layer 1: [8,3] @ [3,100]
        for (int idx = tid; idx < 8 * HH; idx += 256) {
            const int ii = idx / HH, u = idx - ii * HH;
            float acc = rb1[u] + bas[ii][0] * rW1[u] + bas[ii][1] * rW1[HH + u]
                      + bas[ii][2] * rW1[2 * HH + u];
            h1[ii][u] = sp5(acc);
        }
        __syncthreads();
        // layer 2: [8,100] @ [100,100]
        for (int idx = tid; idx < 8 * HH; idx += 256) {
            const int ii = idx / HH, u = idx - ii * HH;
            float acc = rb2[u];
            for (int k = 0; k < HH; ++k) acc += h1[ii][k] * rW2s[k * HH + u];
            h2[ii][u] = sp5(acc);
        }
        __syncthreads();
        // contract: t[lu] = sum_k h2[k] * W3f[k][lu] + tb[lu], scaled 1/sqrt(32)
        for (int idx = tid; idx < 8 * LU; idx += 256) {
            const int ii = idx / LU, lu = idx - ii * LU;
            float acc = tb[lu];
            for (int k = 0; k < HH; ++k) acc += h2[ii][k] * W3f[k * LU + lu];
            const int i = t0 + ii;
            tbuf[((size_t)(b * NN + i) * NN + j) * LU + lu] = acc * 0.17677669529663688f;
        }
        __syncthreads();
    }
}

// ---------------- K2: per-(b,i) block: mask/Y/count + masked contraction ----
__global__ __launch_bounds__(256) void k2_conv(
    const float* __restrict__ xyz, const int* __restrict__ feat,
    const float* __restrict__ emb, const float* __restrict__ tbuf,
    float* __restrict__ feats)
{
    const int b   = blockIdx.x / NN;
    const int i   = blockIdx.x % NN;
    const int tid = threadIdx.x;

    __shared__ float xj[NN * 3];
    __shared__ float maskY[NN][10];
    __shared__ float tl[NN * LU];   // 18432 B
    __shared__ float inv_s;

    if (tid < NN * 3) xj[tid] = xyz[b * NN * 3 + tid];
    __syncthreads();
    const float xix = xj[i * 3 + 0], xiy = xj[i * 3 + 1], xiz = xj[i * 3 + 2];

    if (tid < NN) {
        const int jj = tid;
        const float dx = xj[jj * 3 + 0] - xix;       // rij = xyz[j] - xyz[i]
        const float dy = xj[jj * 3 + 1] - xiy;
        const float dz = xj[jj * 3 + 2] - xiz;
        const float d  = sqrtf(dx * dx + dy * dy + dz * dz + 1e-8f);
        const float m  = (d < 2.0f && jj != i) ? 1.0f : 0.0f;
        const float ux = dx / d, uy = dy / d, uz = dz / d;
        maskY[jj][0] = m * 0.28209479177f;
        maskY[jj][1] = m * 0.48860251190f * uy;
        maskY[jj][2] = m * 0.48860251190f * uz;
        maskY[jj][3] = m * 0.48860251190f * ux;
        maskY[jj][4] = m * 1.09254843059f * ux * uy;
        maskY[jj][5] = m * 1.09254843059f * uy * uz;
        maskY[jj][6] = m * 0.31539156525f * (3.0f * uz * uz - 1.0f);
        maskY[jj][7] = m * 1.09254843059f * ux * uz;
        maskY[jj][8] = m * 0.5f * 1.09254843059f * (ux * ux - uy * uy);
        const unsigned long long bal = __ballot(m > 0.5f);
        if (jj == 0) {
            const float cnt = (float)__popcll(bal);
            inv_s = 1.0f / sqrtf(fmaxf(cnt, 1.0f));
        }
    }
    for (int idx = tid; idx < NN * LU; idx += 256)
        tl[idx] = tbuf[(size_t)blockIdx.x * (NN * LU) + idx];
    __syncthreads();

    if (tid < 216) {
        int l, u, m, yoff;
        if (tid < 24)       { l = 0; u = tid;            m = 0;            yoff = 0; }
        else if (tid < 96)  { const int q = tid - 24; l = 1; u = q / 3; m = q % 3; yoff = 1; }
        else                { const int q = tid - 96; l = 2; u = q / 5; m = q % 5; yoff = 4; }
        const int lu = l * CD + u;
        float acc = 0.f;
        for (int jj = 0; jj < NN; ++jj)
            acc += maskY[jj][yoff + m] * tl[jj * LU + lu];
        feats[(size_t)blockIdx.x * COUT + EMB + tid] = acc * inv_s;
    } else if (tid < 216 + EMB) {
        const int v = tid - 216;
        feats[(size_t)blockIdx.x * COUT + v] = emb[feat[blockIdx.x] * EMB + v];
    }
}

// ---------------- K3: x2pre = feats @ resW + resb  ([512,248]@[248,248]) ----
__global__ __launch_bounds__(256) void k3_resgemm(
    const float* __restrict__ feats, const float* __restrict__ resW,
    const float* __restrict__ resb, float* __restrict__ x2pre)
{
    const int r0  = blockIdx.x * 8;
    const int tid = threadIdx.x;
    __shared__ float fr[8][COUT];
    for (int idx = tid; idx < 8 * COUT; idx += 256)
        fr[idx / COUT][idx % COUT] = feats[(size_t)r0 * COUT + idx];
    __syncthreads();
    if (tid < COUT) {
        const int c = tid;
        float acc[8];
#pragma unroll
        for (int rr = 0; rr < 8; ++rr) acc[rr] = resb[c];
        for (int k = 0; k < COUT; ++k) {
            const float w = resW[k * COUT + c];
#pragma unroll
            for (int rr = 0; rr < 8; ++rr) acc[rr] += fr[rr][k] * w;
        }
#pragma unroll
        for (int rr = 0; rr < 8; ++rr) x2pre[(size_t)(r0 + rr) * COUT + c] = acc[rr];
    }
}

// ---------------- K4: per-column batch stats over 512 rows ------------------
__global__ __launch_bounds__(256) void k4_stats(
    const float* __restrict__ x2pre, float* __restrict__ stats)
{
    const int c   = blockIdx.x;
    const int tid = threadIdx.x;
    float s = 0.f, s2 = 0.f;
    for (int r = tid; r < BB * NN; r += 256) {
        const float v = x2pre[(size_t)r * COUT + c];
        s += v; s2 += v * v;
    }
    __shared__ float rs[256], rq[256];
    rs[tid] = s; rq[tid] = s2;
    __syncthreads();
    for (int off = 128; off > 0; off >>= 1) {
        if (tid < off) { rs[tid] += rs[tid + off]; rq[tid] += rq[tid + off]; }
        __syncthreads();
    }
    if (tid == 0) {
        const float mu  = rs[0] * (1.0f / 512.0f);
        const float var = rq[0] * (1.0f / 512.0f) - mu * mu;
        stats[c]        = mu;
        stats[COUT + c] = 1.0f / sqrtf(var + 1e-5f);
    }
}

// ---------------- K5: normalize+relu, concat, mean-pool over N --------------
__global__ __launch_bounds__(512) void k5_pool(
    const float* __restrict__ feats, const float* __restrict__ x2pre,
    const float* __restrict__ stats,
    const float* __restrict__ gamma, const float* __restrict__ beta,
    float* __restrict__ pooled)
{
    const int b = blockIdx.x;
    const int c = threadIdx.x;
    if (c >= RESO) return;
    float acc = 0.f;
    if (c < COUT) {
        for (int i = 0; i < NN; ++i) acc += feats[(size_t)(b * NN + i) * COUT + c];
    } else {
        const int cc = c - COUT;
        const float mu = stats[cc], rstd = stats[COUT + cc];
        const float g = gamma[cc], be = beta[cc];
        for (int i = 0; i < NN; ++i) {
            const float v = (x2pre[(size_t)(b * NN + i) * COUT + cc] - mu) * rstd * g + be;
            acc += fmaxf(v, 0.f);
        }
    }
    pooled[b * RESO + c] = acc * (1.0f / (float)NN);
}

// ---------------- K6: single-block head: FF GEMM + BN(8) + sigmoid ----------
__global__ __launch_bounds__(256) void k6_head(
    const float* __restrict__ pooled,
    const float* __restrict__ cW, const float* __restrict__ cb,
    const float* __restrict__ c_gamma, const float* __restrict__ c_beta,
    const float* __restrict__ oW, const float* __restrict__ ob,
    float* __restrict__ out)
{
    const int tid = threadIdx.x;
    __shared__ float ps[BB * RESO];    // 15872 B
    __shared__ float hh[BB * FF];      // 4096 B
    for (int idx = tid; idx < BB * RESO; idx += 256) ps[idx] = pooled[idx];
    __syncthreads();
    for (int idx = tid; idx < BB * FF; idx += 256) {
        const int bb = idx / FF, o = idx - bb * FF;
        float acc = cb[o];
        for (int k = 0; k < RESO; ++k) acc += ps[bb * RESO + k] * cW[k * FF + o];
        hh[idx] = (acc >= 0.f) ? acc : 0.01f * acc;
    }
    __syncthreads();
    if (tid < FF) {
        float mu = 0.f;
#pragma unroll
        for (int bb = 0; bb < BB; ++bb) mu += hh[bb * FF + tid];
        mu *= (1.0f / (float)BB);
        float var = 0.f;
#pragma unroll
        for (int bb = 0; bb < BB; ++bb) { const float d = hh[bb * FF + tid] - mu; var += d * d; }
        var *= (1.0f / (float)BB);
        const float rstd = 1.0f / sqrtf(var + 1e-5f);
        const float g = c_gamma[tid], be = c_beta[tid];
#pragma unroll
        for (int bb = 0; bb < BB; ++bb) {
            float v = (hh[bb * FF + tid] - mu) * rstd * g + be;
            hh[bb * FF + tid] = (v >= 0.f) ? v : 0.01f * v;
        }
    }
    __syncthreads();
    if (tid < BB) {
        float acc = ob[0];
        for (int o = 0; o < FF; ++o) acc += hh[tid * FF + o] * oW[o];
        out[tid] = 1.0f / (1.0f + expf(-acc));
    }
}

extern "C" void kernel_launch(void* const* d_in, const int* in_sizes, int n_in,
                              void* d_out, int out_size, void* d_ws, size_t ws_size,
                              hipStream_t stream)
{
    const float* xyz  = (const float*)d_in[0];
    const int*   feat = (const int*)  d_in[1];
    const float* emb  = (const float*)d_in[2];
    const float* rW1  = (const float*)d_in[3];
    const float* rb1  = (const float*)d_in[4];
    const float* rW2  = (const float*)d_in[5];
    const float* rb2  = (const float*)d_in[6];
    const float* rW3  = (const float*)d_in[7];
    const float* rb3  = (const float*)d_in[8];
    const float* resW = (const float*)d_in[9];
    const float* resb = (const float*)d_in[10];
    const float* res_gamma = (const float*)d_in[11];
    const float* res_beta  = (const float*)d_in[12];
    const float* cW   = (const float*)d_in[13];
    const float* cb   = (const float*)d_in[14];
    const float* c_gamma = (const float*)d_in[15];
    const float* c_beta  = (const float*)d_in[16];
    const float* oW   = (const float*)d_in[17];
    const float* ob   = (const float*)d_in[18];
    float* out = (float*)d_out;

    char* ws = (char*)d_ws;
    float* tbuf   = (float*)ws;                                   // 32768*72 = 9.44 MB
    float* feats  = (float*)(ws + (size_t)32768 * 72 * 4);        // 512*248
    float* x2pre  = feats + 512 * COUT;                           // 512*248
    float* stats  = x2pre + 512 * COUT;                           // 2*248
    float* pooled = stats + 2 * COUT;                             // 8*496

    k1_pairs<<<BB * NN, 256, 0, stream>>>(xyz, feat, emb, rW1, rb1, rW2, rb2, rW3, rb3, tbuf);
    k2_conv <<<BB * NN, 256, 0, stream>>>(xyz, feat, emb, tbuf, feats);
    k3_resgemm<<<64, 256, 0, stream>>>(feats, resW, resb, x2pre);
    k4_stats<<<COUT, 256, 0, stream>>>(x2pre, stats);
    k5_pool <<<BB, 512, 0, stream>>>(feats, x2pre, stats, res_gamma, res_beta, pooled);
    k6_head <<<1, 256, 0, stream>>>(pooled, cW, cb, c_gamma, c_beta, oW, ob, out);
}

// Round 4
// 191.855 us; speedup vs baseline: 1.6639x; 1.6639x over previous
//
#include <hip/hip_runtime.h>
#include <hip/hip_bf16.h>

#define BB   8
#define NN   64
#define EMB  32
#define CD   24
#define HH   100
#define LU   72
#define COUT 248
#define RESO 496
#define FF   128

__device__ __forceinline__ float sp5(float x) {
    // softplus(5x)/5 == 0.2*(max(z,0) + log1p(exp(-|z|))), z=5x; fast exp/log ok (abs err ~1e-7)
    float z = 5.0f * x;
    float t = __expf(-fabsf(z));
    return 0.2f * (fmaxf(z, 0.0f) + __logf(1.0f + t));
}
__device__ __forceinline__ float4 ld4(const float* p) { return *reinterpret_cast<const float4*>(p); }
__device__ __forceinline__ void st4(float* p, float4 v) { *reinterpret_cast<float4*>(p) = v; }
__device__ __forceinline__ void fma4(float4& a, float s, float4 w) {
    a.x = fmaf(s, w.x, a.x); a.y = fmaf(s, w.y, a.y);
    a.z = fmaf(s, w.z, a.z); a.w = fmaf(s, w.w, a.w);
}

// ---- K0: W3f_all[t][k][lu] = sum_v rW3[k][lu*32+v]*emb[t][v]; tb_all[t][lu] likewise for rb3
__global__ __launch_bounds__(256) void k0_w3f(
    const float* __restrict__ rW3, const float* __restrict__ rb3,
    const float* __restrict__ emb, float* __restrict__ W3f_all, float* __restrict__ tb_all)
{
    const int t = blockIdx.x / 10, kc = blockIdx.x % 10;
    __shared__ float embt[EMB];
    if (threadIdx.x < EMB) embt[threadIdx.x] = emb[t * EMB + threadIdx.x];
    __syncthreads();
    for (int idx = threadIdx.x; idx < 10 * LU; idx += 256) {
        const int k = kc * 10 + idx / LU, lu = idx % LU;
        const float* w = rW3 + (size_t)k * (LU * EMB) + lu * EMB;
        float acc = 0.f;
#pragma unroll
        for (int v4 = 0; v4 < EMB / 4; ++v4) {
            float4 wv = ld4(w + 4 * v4);
            acc += wv.x * embt[4 * v4] + wv.y * embt[4 * v4 + 1]
                 + wv.z * embt[4 * v4 + 2] + wv.w * embt[4 * v4 + 3];
        }
        W3f_all[(size_t)t * HH * LU + k * LU + lu] = acc;
    }
    if (kc == 0 && threadIdx.x < LU) {
        const float* w = rb3 + threadIdx.x * EMB;
        float acc = 0.f;
        for (int v = 0; v < EMB; ++v) acc += w[v] * embt[v];
        tb_all[t * LU + threadIdx.x] = acc;
    }
}

// ---- K1: block per (b,j); all 64 i; register-tiled 8i x 4u inner loops
__global__ __launch_bounds__(256) void k1_pairs(
    const float* __restrict__ xyz, const int* __restrict__ feat,
    const float* __restrict__ rW1, const float* __restrict__ rb1,
    const float* __restrict__ rW2, const float* __restrict__ rb2,
    const float* __restrict__ W3f_all, const float* __restrict__ tb_all,
    float* __restrict__ tbuf)
{
    const int b = blockIdx.x >> 6, j = blockIdx.x & 63;
    const int tid = threadIdx.x;

    __shared__ __align__(16) float rW2s[HH * HH];   // 40000 B
    __shared__ __align__(16) float W3fs[HH * LU];   // 28800 B
    __shared__ __align__(16) float h1T[HH * NN];    // 25600 B  h1T[k][i]
    __shared__ __align__(16) float h2T[HH * NN];    // 25600 B  h2T[k][i]
    __shared__ __align__(16) float rW1s[3 * HH];    // 1200 B
    __shared__ __align__(16) float rb1s[HH];
    __shared__ __align__(16) float rb2s[HH];
    __shared__ __align__(16) float tbs[LU];
    __shared__ __align__(16) float xi[NN * 3];

    const int type = feat[b * NN + j];
    for (int idx = tid; idx < HH * HH / 4; idx += 256) st4(&rW2s[idx * 4], ld4(&rW2[idx * 4]));
    {
        const float* src = W3f_all + (size_t)type * HH * LU;
        for (int idx = tid; idx < HH * LU / 4; idx += 256) st4(&W3fs[idx * 4], ld4(&src[idx * 4]));
    }
    if (tid < 75)                 st4(&rW1s[tid * 4], ld4(&rW1[tid * 4]));
    if (tid >= 80 && tid < 105)   st4(&rb1s[(tid - 80) * 4], ld4(&rb1[(tid - 80) * 4]));
    if (tid >= 112 && tid < 137)  st4(&rb2s[(tid - 112) * 4], ld4(&rb2[(tid - 112) * 4]));
    if (tid >= 144 && tid < 162)  st4(&tbs[(tid - 144) * 4], ld4(&tb_all[type * LU + (tid - 144) * 4]));
    if (tid >= 168 && tid < 216)  st4(&xi[(tid - 168) * 4], ld4(&xyz[b * NN * 3 + (tid - 168) * 4]));
    __syncthreads();

    // layer1 (+inline basis): thread (ik = i, ug = u-quarter) -> 25 u each
    {
        const int ik = tid & 63, ug = tid >> 6;
        const float dx = xi[j * 3 + 0] - xi[ik * 3 + 0];
        const float dy = xi[j * 3 + 1] - xi[ik * 3 + 1];
        const float dz = xi[j * 3 + 2] - xi[ik * 3 + 2];
        const float d = sqrtf(dx * dx + dy * dy + dz * dz + 1e-8f);
        float bas[3];
#pragma unroll
        for (int r = 0; r < 3; ++r) {
            float u = fabsf(d - (float)r);          // radii {0,1,2}, step 1
            float c = cosf(1.57079632679489662f * u);
            bas[r] = (u < 1.0f) ? c * c : 0.0f;
        }
#pragma unroll
        for (int uu = 0; uu < 25; ++uu) {
            const int u = ug * 25 + uu;
            float v = rb1s[u] + bas[0] * rW1s[u] + bas[1] * rW1s[HH + u] + bas[2] * rW1s[2 * HH + u];
            h1T[u * NN + ik] = sp5(v);
        }
    }
    __syncthreads();

    // layer2: thread (ut<25, ig<8): 4 u x 8 i register tile
    if (tid < 200) {
        const int ut = tid % 25, ig = tid / 25;
        float4 a[8];
        {
            float4 b0 = ld4(&rb2s[4 * ut]);
#pragma unroll
            for (int m = 0; m < 8; ++m) a[m] = b0;
        }
        for (int k = 0; k < HH; ++k) {
            float4 w  = ld4(&rW2s[k * HH + 4 * ut]);
            float4 hA = ld4(&h1T[k * NN + 8 * ig]);
            float4 hB = ld4(&h1T[k * NN + 8 * ig + 4]);
            fma4(a[0], hA.x, w); fma4(a[1], hA.y, w); fma4(a[2], hA.z, w); fma4(a[3], hA.w, w);
            fma4(a[4], hB.x, w); fma4(a[5], hB.y, w); fma4(a[6], hB.z, w); fma4(a[7], hB.w, w);
        }
#pragma unroll
        for (int m = 0; m < 8; ++m) {
            a[m].x = sp5(a[m].x); a[m].y = sp5(a[m].y); a[m].z = sp5(a[m].z); a[m].w = sp5(a[m].w);
        }
        st4(&h2T[(4 * ut + 0) * NN + 8 * ig],     make_float4(a[0].x, a[1].x, a[2].x, a[3].x));
        st4(&h2T[(4 * ut + 0) * NN + 8 * ig + 4], make_float4(a[4].x, a[5].x, a[6].x, a[7].x));
        st4(&h2T[(4 * ut + 1) * NN + 8 * ig],     make_float4(a[0].y, a[1].y, a[2].y, a[3].y));
        st4(&h2T[(4 * ut + 1) * NN + 8 * ig + 4], make_float4(a[4].y, a[5].y, a[6].y, a[7].y));
        st4(&h2T[(4 * ut + 2) * NN + 8 * ig],     make_float4(a[0].z, a[1].z, a[2].z, a[3].z));
        st4(&h2T[(4 * ut + 2) * NN + 8 * ig + 4], make_float4(a[4].z, a[5].z, a[6].z, a[7].z));
        st4(&h2T[(4 * ut + 3) * NN + 8 * ig],     make_float4(a[0].w, a[1].w, a[2].w, a[3].w));
        st4(&h2T[(4 * ut + 3) * NN + 8 * ig + 4], make_float4(a[4].w, a[5].w, a[6].w, a[7].w));
    }
    __syncthreads();

    // contract: thread (lut<18, ig<8): 4 lu x 8 i register tile; t = h2 . W3f + tb
    if (tid < 144) {
        const int lut = tid % 18, ig = tid / 18;
        float4 a[8];
        {
            float4 t0 = ld4(&tbs[4 * lut]);
#pragma unroll
            for (int m = 0; m < 8; ++m) a[m] = t0;
        }
        for (int k = 0; k < HH; ++k) {
            float4 w  = ld4(&W3fs[k * LU + 4 * lut]);
            float4 hA = ld4(&h2T[k * NN + 8 * ig]);
            float4 hB = ld4(&h2T[k * NN + 8 * ig + 4]);
            fma4(a[0], hA.x, w); fma4(a[1], hA.y, w); fma4(a[2], hA.z, w); fma4(a[3], hA.w, w);
            fma4(a[4], hB.x, w); fma4(a[5], hB.y, w); fma4(a[6], hB.z, w); fma4(a[7], hB.w, w);
        }
        const float s = 0.17677669529663688f;   // 1/sqrt(32)
#pragma unroll
        for (int m = 0; m < 8; ++m) {
            const int i = 8 * ig + m;
            float* dst = (float*)&tbuf[((size_t)(b * NN + i) * NN + j) * LU + 4 * lut];
            st4(dst, make_float4(a[m].x * s, a[m].y * s, a[m].z * s, a[m].w * s));
        }
    }
}

// ---- K2: block per (b,i): mask/Y + conv contraction + feats + fused res-GEMV
__global__ __launch_bounds__(256) void k2_conv(
    const float* __restrict__ xyz, const int* __restrict__ feat,
    const float* __restrict__ emb, const float* __restrict__ tbuf,
    const float* __restrict__ resW, const float* __restrict__ resb,
    float* __restrict__ feats, float* __restrict__ x2pre)
{
    const int b = blockIdx.x >> 6, i = blockIdx.x & 63;
    const int tid = threadIdx.x;
    __shared__ __align__(16) float xj[NN * 3];
    __shared__ __align__(16) float mYT[9 * 68];    // maskY transposed, padded rows
    __shared__ __align__(16) float tlT[LU * 68];   // t transposed [lu][jj]
    __shared__ __align__(16) float fs[COUT];
    __shared__ float inv_s;

    if (tid < 48) st4(&xj[tid * 4], ld4(&xyz[b * NN * 3 + tid * 4]));
    if (tid >= 64 && tid < 96) fs[tid - 64] = emb[feat[b * NN + i] * EMB + (tid - 64)];
    {   // stage + transpose t row-block (no dependence on xj)
        const float* src = tbuf + (size_t)blockIdx.x * (NN * LU);
        for (int idx = tid; idx < NN * LU; idx += 256) {
            const int jj = idx / LU, lu = idx - jj * LU;
            tlT[lu * 68 + jj] = src[idx];
        }
    }
    __syncthreads();
    if (tid < 64) {
        const int jj = tid;
        float dx = xj[jj * 3 + 0] - xj[i * 3 + 0];
        float dy = xj[jj * 3 + 1] - xj[i * 3 + 1];
        float dz = xj[jj * 3 + 2] - xj[i * 3 + 2];
        float d = sqrtf(dx * dx + dy * dy + dz * dz + 1e-8f);
        float m = (d < 2.0f && jj != i) ? 1.0f : 0.0f;
        float ux = dx / d, uy = dy / d, uz = dz / d;
        mYT[0 * 68 + jj] = m * 0.28209479177f;
        mYT[1 * 68 + jj] = m * 0.48860251190f * uy;
        mYT[2 * 68 + jj] = m * 0.48860251190f * uz;
        mYT[3 * 68 + jj] = m * 0.48860251190f * ux;
        mYT[4 * 68 + jj] = m * 1.09254843059f * ux * uy;
        mYT[5 * 68 + jj] = m * 1.09254843059f * uy * uz;
        mYT[6 * 68 + jj] = m * 0.31539156525f * (3.0f * uz * uz - 1.0f);
        mYT[7 * 68 + jj] = m * 1.09254843059f * ux * uz;
        mYT[8 * 68 + jj] = m * 0.54627421529f * (ux * ux - uy * uy);
        unsigned long long bal = __ballot(m > 0.5f);
        if (jj == 0) inv_s = rsqrtf(fmaxf((float)__popcll(bal), 1.0f));
    }
    __syncthreads();

    if (tid < 216) {
        int l, u, m, yoff;
        if (tid < 24)      { l = 0; u = tid; m = 0; yoff = 0; }
        else if (tid < 96) { int q = tid - 24; l = 1; u = q / 3; m = q % 3; yoff = 1; }
        else               { int q = tid - 96; l = 2; u = q / 5; m = q % 5; yoff = 4; }
        const int lu = l * CD + u, yr = yoff + m;
        float acc = 0.f;
#pragma unroll
        for (int j4 = 0; j4 < 16; ++j4) {
            float4 y = ld4(&mYT[yr * 68 + 4 * j4]);
            float4 t = ld4(&tlT[lu * 68 + 4 * j4]);
            acc += y.x * t.x + y.y * t.y + y.z * t.z + y.w * t.w;
        }
        fs[EMB + tid] = acc * inv_s;
    }
    __syncthreads();

    const size_t row = (size_t)blockIdx.x;
    for (int c = tid; c < COUT; c += 256) feats[row * COUT + c] = fs[c];
    if (tid < COUT) {
        float acc = resb[tid];
        for (int k = 0; k < COUT; ++k) acc = fmaf(fs[k], resW[k * COUT + tid], acc);
        x2pre[row * COUT + tid] = acc;
    }
}

// ---- K4: per-column batch stats over 512 rows
__global__ __launch_bounds__(256) void k4_stats(
    const float* __restrict__ x2pre, float* __restrict__ stats)
{
    const int c = blockIdx.x, tid = threadIdx.x;
    float s = 0.f, s2 = 0.f;
    for (int r = tid; r < BB * NN; r += 256) {
        const float v = x2pre[(size_t)r * COUT + c];
        s += v; s2 += v * v;
    }
    __shared__ float rs[256], rq[256];
    rs[tid] = s; rq[tid] = s2;
    __syncthreads();
    for (int off = 128; off > 0; off >>= 1) {
        if (tid < off) { rs[tid] += rs[tid + off]; rq[tid] += rq[tid + off]; }
        __syncthreads();
    }
    if (tid == 0) {
        const float mu = rs[0] * (1.0f / 512.0f);
        const float var = rq[0] * (1.0f / 512.0f) - mu * mu;
        stats[c] = mu;
        stats[COUT + c] = 1.0f / sqrtf(var + 1e-5f);
    }
}

// ---- K5: normalize+relu, concat, mean-pool; writes pooled TRANSPOSED [c][b]
__global__ __launch_bounds__(512) void k5_pool(
    const float* __restrict__ feats, const float* __restrict__ x2pre,
    const float* __restrict__ stats,
    const float* __restrict__ gamma, const float* __restrict__ beta,
    float* __restrict__ pooledT)
{
    const int b = blockIdx.x, c = threadIdx.x;
    if (c >= RESO) return;
    float acc = 0.f;
    if (c < COUT) {
        for (int i = 0; i < NN; ++i) acc += feats[(size_t)(b * NN + i) * COUT + c];
    } else {
        const int cc = c - COUT;
        const float mu = stats[cc], rstd = stats[COUT + cc];
        const float g = gamma[cc], be = beta[cc];
        for (int i = 0; i < NN; ++i) {
            const float v = (x2pre[(size_t)(b * NN + i) * COUT + cc] - mu) * rstd * g + be;
            acc += fmaxf(v, 0.f);
        }
    }
    pooledT[c * BB + b] = acc * (1.0f / (float)NN);
}

// ---- K6: 128 threads, thread per output o; BN(8) fully in registers
__global__ __launch_bounds__(128) void k6_head(
    const float* __restrict__ pooledT,
    const float* __restrict__ cW, const float* __restrict__ cb,
    const float* __restrict__ c_gamma, const float* __restrict__ c_beta,
    const float* __restrict__ oW, const float* __restrict__ ob,
    float* __restrict__ out)
{
    const int o = threadIdx.x;
    __shared__ __align__(16) float psT[RESO * BB];  // 15872 B
    __shared__ __align__(16) float red[FF * BB];    // 4096 B
    for (int idx = o; idx < RESO * BB / 4; idx += 128) st4(&psT[idx * 4], ld4(&pooledT[idx * 4]));
    __syncthreads();
    float4 aA = make_float4(0.f, 0.f, 0.f, 0.f), aB = aA;
    for (int k = 0; k < RESO; ++k) {
        float w = cW[k * FF + o];
        float4 pA = ld4(&psT[k * BB]);
        float4 pB = ld4(&psT[k * BB + 4]);
        fma4(aA, w, pA); fma4(aB, w, pB);
    }
    const float cbv = cb[o];
    float h[8] = { aA.x + cbv, aA.y + cbv, aA.z + cbv, aA.w + cbv,
                   aB.x + cbv, aB.y + cbv, aB.z + cbv, aB.w + cbv };
    float mu = 0.f;
#pragma unroll
    for (int q = 0; q < 8; ++q) { h[q] = (h[q] >= 0.f) ? h[q] : 0.01f * h[q]; mu += h[q]; }
    mu *= 0.125f;
    float var = 0.f;
#pragma unroll
    for (int q = 0; q < 8; ++q) { float dd = h[q] - mu; var += dd * dd; }
    var *= 0.125f;
    const float rstd = 1.0f / sqrtf(var + 1e-5f);
    const float g = c_gamma[o], be = c_beta[o], wo = oW[o];
#pragma unroll
    for (int q = 0; q < 8; ++q) {
        float v = (h[q] - mu) * rstd * g + be;
        h[q] = ((v >= 0.f) ? v : 0.01f * v) * wo;
    }
    st4(&red[o * 8],     make_float4(h[0], h[1], h[2], h[3]));
    st4(&red[o * 8 + 4], make_float4(h[4], h[5], h[6], h[7]));
    __syncthreads();
    for (int off = 64; off >= 1; off >>= 1) {
        if (o < off) {
            float4 x0 = ld4(&red[o * 8]),     y0 = ld4(&red[(o + off) * 8]);
            float4 x1 = ld4(&red[o * 8 + 4]), y1 = ld4(&red[(o + off) * 8 + 4]);
            st4(&red[o * 8],     make_float4(x0.x + y0.x, x0.y + y0.y, x0.z + y0.z, x0.w + y0.w));
            st4(&red[o * 8 + 4], make_float4(x1.x + y1.x, x1.y + y1.y, x1.z + y1.z, x1.w + y1.w));
        }
        __syncthreads();
    }
    if (o < BB) out[o] = 1.0f / (1.0f + __expf(-(red[o] + ob[0])));
}

extern "C" void kernel_launch(void* const* d_in, const int* in_sizes, int n_in,
                              void* d_out, int out_size, void* d_ws, size_t ws_size,
                              hipStream_t stream)
{
    const float* xyz  = (const float*)d_in[0];
    const int*   feat = (const int*)  d_in[1];
    const float* emb  = (const float*)d_in[2];
    const float* rW1  = (const float*)d_in[3];
    const float* rb1  = (const float*)d_in[4];
    const float* rW2  = (const float*)d_in[5];
    const float* rb2  = (const float*)d_in[6];
    const float* rW3  = (const float*)d_in[7];
    const float* rb3  = (const float*)d_in[8];
    const float* resW = (const float*)d_in[9];
    const float* resb = (const float*)d_in[10];
    const float* res_gamma = (const float*)d_in[11];
    const float* res_beta  = (const float*)d_in[12];
    const float* cW   = (const float*)d_in[13];
    const float* cb   = (const float*)d_in[14];
    const float* c_gamma = (const float*)d_in[15];
    const float* c_beta  = (const float*)d_in[16];
    const float* oW   = (const float*)d_in[17];
    const float* ob   = (const float*)d_in[18];
    float* out = (float*)d_out;

    char* ws = (char*)d_ws;
    float* tbuf    = (float*)ws;                                   // 8*64*64*72*4 = 9,437,184 B
    float* W3f_all = (float*)(ws + 9437184);                       // 6*100*72*4 = 172,800 B
    float* tb_all  = (float*)(ws + 9437184 + 172800);              // 6*72*4 = 1,728 B
    float* feats   = (float*)(ws + 9437184 + 172800 + 1728);       // 512*248*4 = 507,904 B
    float* x2pre   = feats + 512 * COUT;
    float* stats   = x2pre + 512 * COUT;                           // 2*248
    float* pooledT = stats + 2 * COUT;                             // 496*8

    k0_w3f  <<<60, 256, 0, stream>>>(rW3, rb3, emb, W3f_all, tb_all);
    k1_pairs<<<BB * NN, 256, 0, stream>>>(xyz, feat, rW1, rb1, rW2, rb2, W3f_all, tb_all, tbuf);
    k2_conv <<<BB * NN, 256, 0, stream>>>(xyz, feat, emb, tbuf, resW, resb, feats, x2pre);
    k4_stats<<<COUT, 256, 0, stream>>>(x2pre, stats);
    k5_pool <<<BB, 512, 0, stream>>>(feats, x2pre, stats, res_gamma, res_beta, pooledT);
    k6_head <<<1, 128, 0, stream>>>(pooledT, cW, cb, c_gamma, c_beta, oW, ob, out);
}